// Round 9
// baseline (1160.418 us; speedup 1.0000x reference)
//
#include <hip/hip_runtime.h>
#include <hip/hip_bf16.h>
#include <math.h>

#define BN_EPS 1e-5f

typedef __attribute__((ext_vector_type(8))) short bf16x8;
typedef __attribute__((ext_vector_type(4))) float f32x4;
typedef unsigned int uint32;

// ---------------- bf16 helpers ----------------
__device__ __forceinline__ unsigned bf16rne(float f) {
  unsigned u = __float_as_uint(f);
  unsigned r = u + 0x7fffu + ((u >> 16) & 1u);
  return r >> 16;
}
__device__ __forceinline__ float bf2f_lo(uint32 u) { return __uint_as_float(u << 16); }
__device__ __forceinline__ float bf2f_hi(uint32 u) { return __uint_as_float(u & 0xffff0000u); }
__device__ __forceinline__ uint32 packbf2(float a, float b) {
  return bf16rne(a) | (bf16rne(b) << 16);
}

// ---------------- edge index access (int32 vs int64 layout), non-temporal ----------------
__device__ __forceinline__ int edge_at_nt(const int* __restrict__ ei, long long idx, int is64) {
  return is64 ? __builtin_nontemporal_load(ei + 2 * idx)
              : __builtin_nontemporal_load(ei + idx);
}

__global__ void detect_kernel(const int* __restrict__ ei, long long E, int* __restrict__ flag) {
  __shared__ int found;
  int t = threadIdx.x;
  if (t == 0) found = 0;
  __syncthreads();
  long long npairs = E < 1024 ? E : 1024;
  for (long long p = t; p < npairs; p += blockDim.x)
    if (ei[2 * p + 1] != 0) found = 1;
  __syncthreads();
  if (t == 0) *flag = found ? 0 : 1;  // all hi-words zero => int64
}

// ---------------- utility zero kernels ----------------
__global__ void zero_i32_kernel(int* __restrict__ p, long long n) {
  long long i = blockIdx.x * (long long)blockDim.x + threadIdx.x;
  if (i < n) p[i] = 0;
}
__global__ void zero_f32_kernel(float* __restrict__ p, long long n) {
  long long i = blockIdx.x * (long long)blockDim.x + threadIdx.x;
  if (i < n) p[i] = 0.f;
}

// ---------------- CSR build ----------------
// Pass 1: extract src, XCD-sharded count (shadow = blockIdx&7), record shadow-rank.
// All streaming traffic is non-temporal so the hot cnt8 histogram stays L2-resident.
__global__ void extract_count_kernel(const int* __restrict__ ei, long long E,
                                     const int* __restrict__ flag,
                                     int* __restrict__ es, int* __restrict__ r8,
                                     int* __restrict__ cnt8, int N) {
  long long e = blockIdx.x * (long long)blockDim.x + threadIdx.x;
  if (e >= E) return;
  int is64 = *flag;
  int sv = edge_at_nt(ei, e, is64);
  int d = edge_at_nt(ei, E + e, is64);
  __builtin_nontemporal_store(sv, es + e);
  int sh = blockIdx.x & 7;
  int r = atomicAdd(&cnt8[(size_t)sh * N + d], 1);
  __builtin_nontemporal_store(r, r8 + e);
}

// per-node exclusive prefix across shadows; total degree -> cnt_node
__global__ void cumnode_kernel(const int* __restrict__ cnt8, int* __restrict__ cum8,
                               int* __restrict__ cnt_node, int N) {
  int n = blockIdx.x * blockDim.x + threadIdx.x;
  if (n >= N) return;
  int run = 0;
#pragma unroll
  for (int sh = 0; sh < 8; ++sh) {
    int c = cnt8[(size_t)sh * N + n];
    cum8[(size_t)sh * N + n] = run;
    run += c;
  }
  cnt_node[n] = run;
}

// ---- two-level scan ----
__global__ void partial_kernel(const int* __restrict__ cnt, int* __restrict__ bsum, int M) {
  __shared__ int s[256];
  int b = blockIdx.x, t = threadIdx.x;
  int base = b * 2048 + t * 8;
  int sum = 0;
#pragma unroll
  for (int i = 0; i < 8; ++i) {
    int idx = base + i;
    if (idx < M) sum += cnt[idx];
  }
  s[t] = sum;
  __syncthreads();
  for (int d = 128; d > 0; d >>= 1) {
    if (t < d) s[t] += s[t + d];
    __syncthreads();
  }
  if (t == 0) bsum[b] = s[0];
}

__global__ void scanb_kernel(int* __restrict__ bsum, int nb) {
  __shared__ int s[512];
  int t = threadIdx.x;
  int v = (t < nb) ? bsum[t] : 0;
  s[t] = v;
  __syncthreads();
  for (int d = 1; d < 512; d <<= 1) {
    int u = (t >= d) ? s[t - d] : 0;
    __syncthreads();
    s[t] += u;
    __syncthreads();
  }
  if (t < nb) bsum[t] = s[t] - v;  // exclusive
}

__global__ void offsets_kernel(const int* __restrict__ cnt, const int* __restrict__ bsum,
                               int* __restrict__ off, int M, long long Etot) {
  __shared__ int s[256];
  int b = blockIdx.x, t = threadIdx.x;
  int base = b * 2048 + t * 8;
  int v[8];
  int sum = 0;
#pragma unroll
  for (int i = 0; i < 8; ++i) {
    int idx = base + i;
    v[i] = (idx < M) ? cnt[idx] : 0;
    sum += v[i];
  }
  s[t] = sum;
  __syncthreads();
  for (int d = 1; d < 256; d <<= 1) {
    int u = (t >= d) ? s[t - d] : 0;
    __syncthreads();
    s[t] += u;
    __syncthreads();
  }
  int run = bsum[b] + s[t] - sum;
#pragma unroll
  for (int i = 0; i < 8; ++i) {
    int idx = base + i;
    if (idx < M) {
      off[idx] = run;
      run += v[i];
    }
  }
  if (b == 0 && t == 0) off[M] = (int)Etot;
}

// pos[e] = off_node[d] + cum8[sh][d] + r8[e]; pack region (d>>15, N<=131072) in bits 28+.
// streaming (ei, r8, ppk) non-temporal; hot tables (off_node, cum8) cached.
__global__ void pos_kernel(const int* __restrict__ ei, long long E, const int* __restrict__ flag,
                           const int* __restrict__ r8, const int* __restrict__ off_node,
                           const int* __restrict__ cum8, uint32* __restrict__ ppk, int N) {
  long long e = blockIdx.x * (long long)blockDim.x + threadIdx.x;
  if (e >= E) return;
  int is64 = *flag;
  int d = edge_at_nt(ei, E + e, is64);
  int sh = blockIdx.x & 7;  // must match extract_count grid mapping
  int r = __builtin_nontemporal_load(r8 + e);
  uint32 pos = (uint32)(off_node[d] + cum8[(size_t)sh * N + d] + r);
  uint32 region = (uint32)d >> 15;
  __builtin_nontemporal_store(pos | (region << 28), ppk + e);
}

// deterministic region-pass scatter: no atomics; writes land node-major in a
// ~3.2 MB L2-resident window per pass (full-degree buckets -> full lines).
// esrc store stays REGULAR (L2 write-combining in the window is the win).
__global__ void scatter_det_kernel(const int* __restrict__ es, const uint32* __restrict__ ppk,
                                   long long E, uint32 p, int* __restrict__ esrc) {
  long long e = blockIdx.x * (long long)blockDim.x + threadIdx.x;
  if (e >= E) return;
  uint32 v = __builtin_nontemporal_load(ppk + e);
  if ((v >> 28) == p) esrc[v & 0x0FFFFFFFu] = __builtin_nontemporal_load(es + e);
}

// ---------------- fp32 -> packed bf16 rows ----------------
__global__ void convert_bf16_kernel(const float* __restrict__ x, uint32* __restrict__ xb,
                                    long long total2) {
  long long i = blockIdx.x * (long long)blockDim.x + threadIdx.x;
  if (i >= total2) return;
  float2 f = ((const float2*)x)[i];
  xb[i] = packbf2(f.x, f.y);
}

// ---------------- weight repack: W[128][128] fp32 -> b-frag-packed bf16 ----------------
__global__ void repack_w_kernel(const float* __restrict__ W, ushort* __restrict__ Wp) {
  int s = blockIdx.x * 256 + threadIdx.x;
  if (s >= 2048) return;
  int nt = s >> 8, rem = s & 255, ks = rem >> 6, lane = rem & 63;
  int q = lane >> 4, l16 = lane & 15;
  int kbase = ks * 32 + q * 8, c = nt * 16 + l16;
  uint32 out[4];
#pragma unroll
  for (int jp = 0; jp < 4; ++jp) {
    float a = W[(size_t)(kbase + 2 * jp) * 128 + c];
    float b = W[(size_t)(kbase + 2 * jp + 1) * 128 + c];
    out[jp] = packbf2(a, b);
  }
  ((uint4*)Wp)[s] = make_uint4(out[0], out[1], out[2], out[3]);
}

// ---------------- mean aggregation (bf16): one wave per node, 1 dword/lane ----------------
// esrc reads non-temporal (no reuse) so X rows keep the L2.
__global__ void aggregate_bf16_kernel(const uint32* __restrict__ X, const int* __restrict__ off,
                                      const int* __restrict__ esrc, uint32* __restrict__ out,
                                      int N) {
  int gw = (int)((blockIdx.x * (long long)blockDim.x + threadIdx.x) >> 6);
  int lane = threadIdx.x & 63;
  if (gw >= N) return;
  int b = off[gw], e = off[gw + 1];
  float ax = 0.f, ay = 0.f;
  int i = b;
  for (; i + 4 <= e; i += 4) {
    int s0 = __builtin_nontemporal_load(esrc + i + 0);
    int s1 = __builtin_nontemporal_load(esrc + i + 1);
    int s2 = __builtin_nontemporal_load(esrc + i + 2);
    int s3 = __builtin_nontemporal_load(esrc + i + 3);
    uint32 v0 = X[(size_t)s0 * 64 + lane];
    uint32 v1 = X[(size_t)s1 * 64 + lane];
    uint32 v2 = X[(size_t)s2 * 64 + lane];
    uint32 v3 = X[(size_t)s3 * 64 + lane];
    ax += bf2f_lo(v0) + bf2f_lo(v1) + bf2f_lo(v2) + bf2f_lo(v3);
    ay += bf2f_hi(v0) + bf2f_hi(v1) + bf2f_hi(v2) + bf2f_hi(v3);
  }
  for (; i < e; ++i) {
    int s0 = __builtin_nontemporal_load(esrc + i);
    uint32 v0 = X[(size_t)s0 * 64 + lane];
    ax += bf2f_lo(v0); ay += bf2f_hi(v0);
  }
  float inv = 1.0f / fmaxf((float)(e - b), 1.0f);
  out[(size_t)gw * 64 + lane] = packbf2(ax * inv, ay * inv);
}

// ---------------- MFMA GEMM: Y = A1@W1 + A2@W2 + bias ; optional R = A2@W3 + rbias ----------------
__launch_bounds__(256)
__global__ void gemm_mfma_kernel(const ushort* __restrict__ A1, const ushort* __restrict__ W1p,
                                 const ushort* __restrict__ A2, const ushort* __restrict__ W2p,
                                 const ushort* __restrict__ W3p,
                                 const float* __restrict__ bias, const float* __restrict__ rbias,
                                 ushort* __restrict__ Y, ushort* __restrict__ R,
                                 float* __restrict__ bnsum, int N) {
  __shared__ float sred[16][128];
  int t = threadIdx.x;
  int w = t >> 6, lane = t & 63;
  int quad = lane >> 4, l16 = lane & 15;
  int row0 = blockIdx.x * 64 + w * 16;

  f32x4 accY[8], accR[8];
#pragma unroll
  for (int nt = 0; nt < 8; ++nt) {
    accY[nt][0] = accY[nt][1] = accY[nt][2] = accY[nt][3] = 0.f;
    accR[nt][0] = accR[nt][1] = accR[nt][2] = accR[nt][3] = 0.f;
  }

  int rowA = row0 + l16;
  if (rowA > N - 1) rowA = N - 1;
  const ushort* a1p = A1 + (size_t)rowA * 128 + quad * 8;
  const ushort* a2p = A2 + (size_t)rowA * 128 + quad * 8;
  const int haveR = (W3p != nullptr);

#pragma unroll
  for (int ks = 0; ks < 4; ++ks) {
    bf16x8 a = *(const bf16x8*)(a1p + ks * 32);
#pragma unroll
    for (int nt = 0; nt < 8; ++nt) {
      bf16x8 b = *(const bf16x8*)(W1p + ((size_t)(nt * 4 + ks) * 64 + lane) * 8);
      accY[nt] = __builtin_amdgcn_mfma_f32_16x16x32_bf16(a, b, accY[nt], 0, 0, 0);
    }
  }
#pragma unroll
  for (int ks = 0; ks < 4; ++ks) {
    bf16x8 a = *(const bf16x8*)(a2p + ks * 32);
#pragma unroll
    for (int nt = 0; nt < 8; ++nt) {
      bf16x8 b = *(const bf16x8*)(W2p + ((size_t)(nt * 4 + ks) * 64 + lane) * 8);
      accY[nt] = __builtin_amdgcn_mfma_f32_16x16x32_bf16(a, b, accY[nt], 0, 0, 0);
    }
    if (haveR) {
#pragma unroll
      for (int nt = 0; nt < 8; ++nt) {
        bf16x8 b = *(const bf16x8*)(W3p + ((size_t)(nt * 4 + ks) * 64 + lane) * 8);
        accR[nt] = __builtin_amdgcn_mfma_f32_16x16x32_bf16(a, b, accR[nt], 0, 0, 0);
      }
    }
  }

  float s1v[8], s2v[8];
#pragma unroll
  for (int nt = 0; nt < 8; ++nt) {
    int c = nt * 16 + l16;
    float bv = bias[c];
    s1v[nt] = 0.f; s2v[nt] = 0.f;
#pragma unroll
    for (int reg = 0; reg < 4; ++reg) {
      int grow = row0 + quad * 4 + reg;
      if (grow < N) {
        float v = accY[nt][reg] + bv;
        Y[(size_t)grow * 128 + c] = (ushort)bf16rne(v);
        s1v[nt] += v; s2v[nt] += v * v;
      }
    }
    if (haveR) {
      float rb = rbias[c];
#pragma unroll
      for (int reg = 0; reg < 4; ++reg) {
        int grow = row0 + quad * 4 + reg;
        if (grow < N) {
          float v = accR[nt][reg] + rb;
          R[(size_t)grow * 128 + c] = (ushort)bf16rne(v);
        }
      }
    }
  }

  int rrow = w * 4 + quad;
#pragma unroll
  for (int nt = 0; nt < 8; ++nt) sred[rrow][nt * 16 + l16] = s1v[nt];
  __syncthreads();
  if (t < 128) {
    float tot = 0.f;
#pragma unroll
    for (int r16 = 0; r16 < 16; ++r16) tot += sred[r16][t];
    atomicAdd(&bnsum[(size_t)(blockIdx.x & 63) * 256 + t], tot);
  }
  __syncthreads();
#pragma unroll
  for (int nt = 0; nt < 8; ++nt) sred[rrow][nt * 16 + l16] = s2v[nt];
  __syncthreads();
  if (t < 128) {
    float tot = 0.f;
#pragma unroll
    for (int r16 = 0; r16 < 16; ++r16) tot += sred[r16][t];
    atomicAdd(&bnsum[(size_t)(blockIdx.x & 63) * 256 + 128 + t], tot);
  }
}

// ---------------- BN finalize over 64 shadows ----------------
__global__ void bn_finalize_kernel(const float* __restrict__ bnsum, float* __restrict__ bnp, int N) {
  int t = threadIdx.x;
  if (t < 128) {
    float s = 0.f, s2 = 0.f;
    for (int sh = 0; sh < 64; ++sh) {
      s  += bnsum[(size_t)sh * 256 + t];
      s2 += bnsum[(size_t)sh * 256 + 128 + t];
    }
    float invN = 1.0f / (float)N;
    float mu = s * invN;
    float var = s2 * invN - mu * mu;
    bnp[t] = mu;
    bnp[128 + t] = rsqrtf(var + BN_EPS);
  }
}

// ---------------- BN apply + ELU (+ residual), bf16 in/out ----------------
__global__ void bn_elu_kernel(const uint32* __restrict__ Y, const float* __restrict__ bnp,
                              const float* __restrict__ g, const float* __restrict__ be,
                              const uint32* __restrict__ res, uint32* __restrict__ Xo,
                              long long total2) {
  long long i = blockIdx.x * (long long)blockDim.x + threadIdx.x;
  if (i >= total2) return;
  int c0 = (int)(i & 63) * 2;
  uint32 y = __builtin_nontemporal_load(Y + i);
  float v0 = g[c0]     * (bf2f_lo(y) - bnp[c0])     * bnp[128 + c0]     + be[c0];
  float v1 = g[c0 + 1] * (bf2f_hi(y) - bnp[c0 + 1]) * bnp[128 + c0 + 1] + be[c0 + 1];
  v0 = v0 > 0.f ? v0 : expm1f(v0);
  v1 = v1 > 0.f ? v1 : expm1f(v1);
  if (res) {
    uint32 rv = __builtin_nontemporal_load(res + i);
    v0 += bf2f_lo(rv); v1 += bf2f_hi(rv);
  }
  Xo[i] = packbf2(v0, v1);
}

// ---------------- layer 4: z = x3@W4l, rr = x3@W4r (one wave per node) ----------------
__global__ void dot4_kernel(const uint32* __restrict__ X, const float* __restrict__ W4l,
                            const float* __restrict__ W4r, float* __restrict__ z,
                            float* __restrict__ rr, int N) {
  int gw = (int)((blockIdx.x * (long long)blockDim.x + threadIdx.x) >> 6);
  int lane = threadIdx.x & 63;
  if (gw >= N) return;
  uint32 u = X[(size_t)gw * 64 + lane];
  float x0 = bf2f_lo(u), x1 = bf2f_hi(u);
  float wl0 = W4l[2 * lane], wl1 = W4l[2 * lane + 1];
  float wr0 = W4r[2 * lane], wr1 = W4r[2 * lane + 1];
  float a = x0 * wl0 + x1 * wl1;
  float b = x0 * wr0 + x1 * wr1;
  for (int d = 32; d > 0; d >>= 1) {
    a += __shfl_down(a, d, 64);
    b += __shfl_down(b, d, 64);
  }
  if (lane == 0) { z[gw] = a; rr[gw] = b; }
}

// ---------------- layer 4 final: out = mean_agg(z) + b4 + rr ----------------
__global__ void final_kernel(const float* __restrict__ z, const float* __restrict__ rr,
                             const int* __restrict__ off, const int* __restrict__ esrc,
                             const float* __restrict__ b4, float* __restrict__ out, int N) {
  int n = blockIdx.x * blockDim.x + threadIdx.x;
  if (n >= N) return;
  int b = off[n], e = off[n + 1];
  float s = 0.f;
  for (int i = b; i < e; ++i) s += z[__builtin_nontemporal_load(esrc + i)];
  out[n] = s / fmaxf((float)(e - b), 1.0f) + b4[0] + rr[n];
}

// ---------------- launch ----------------
extern "C" void kernel_launch(void* const* d_in, const int* in_sizes, int n_in,
                              void* d_out, int out_size, void* d_ws, size_t ws_size,
                              hipStream_t stream) {
  const float* x   = (const float*)d_in[0];
  const int*   ei  = (const int*)d_in[1];
  const float* W1l = (const float*)d_in[2];
  const float* b1  = (const float*)d_in[3];
  const float* W1r = (const float*)d_in[4];
  const float* W2l = (const float*)d_in[5];
  const float* b2  = (const float*)d_in[6];
  const float* W2r = (const float*)d_in[7];
  const float* W3l = (const float*)d_in[8];
  const float* b3  = (const float*)d_in[9];
  const float* W3r = (const float*)d_in[10];
  const float* W4l = (const float*)d_in[11];
  const float* b4  = (const float*)d_in[12];
  const float* W4r = (const float*)d_in[13];
  const float* g1  = (const float*)d_in[14];
  const float* be1 = (const float*)d_in[15];
  const float* g2  = (const float*)d_in[16];
  const float* be2 = (const float*)d_in[17];
  const float* g3  = (const float*)d_in[18];
  const float* be3 = (const float*)d_in[19];
  const float* Wlin= (const float*)d_in[20];
  const float* blin= (const float*)d_in[21];

  const int N = in_sizes[0] / 128;
  const long long E = in_sizes[1] / 2;
  const int M = 8 * N;
  float* out = (float*)d_out;

  char* w = (char*)d_ws;
  size_t o = 0;
  auto alloc = [&](size_t bytes) -> char* {
    char* p = w + o;
    o = (o + bytes + 255) & ~(size_t)255;
    return p;
  };
  // ---- dedicated (persistent) ----
  int*    off_node = (int*)alloc((size_t)(N + 1) * 4);
  int*    cnt_node = (int*)alloc((size_t)N * 4);
  int*    bsum     = (int*)alloc(512 * 4);
  int*    flag     = (int*)alloc(4);
  float*  bnsum    = (float*)alloc((size_t)64 * 256 * 4);
  float*  bnp      = (float*)alloc(256 * 4);
  float*  z        = (float*)alloc((size_t)N * 4);
  float*  rr       = (float*)alloc((size_t)N * 4);
  ushort* Wp       = (ushort*)alloc((size_t)7 * 2048 * 16);
  int*    esrc     = (int*)alloc((size_t)E * 4);   // final node-major edge list
  // ---- arena slots (lifetime-aliased) ----
  size_t slotA = (size_t)2 * E * 4;                // es | r8 -> later Ybuf
  size_t ysz = (size_t)N * 256;
  if (ysz > slotA) slotA = ysz;
  char* poolA  = alloc(slotA);
  char* poolB1 = alloc((size_t)N * 256);           // cnt8|cum8|ppk -> later B1
  char* poolB3 = alloc((size_t)N * 256);           // -> B3
  uint32* B2   = (uint32*)alloc((size_t)N * 256);
  (void)ws_size; (void)n_in; (void)out_size;

  int*    es    = (int*)poolA;
  int*    r8    = (int*)(poolA + (size_t)E * 4);
  ushort* Ybuf  = (ushort*)poolA;
  int*    cnt8  = (int*)poolB1;                    // 8N ints
  int*    cum8  = cnt8 + M;                        // 8N ints
  uint32* ppk   = (uint32*)(cum8 + M);             // E uints
  uint32* B1    = (uint32*)poolB1;
  uint32* B3    = (uint32*)poolB3;

  const int B = 256;
  const int eb  = (int)((E + B - 1) / B);
  const int nb  = (N + B - 1) / B;
  const int wb  = (int)(((long long)N * 64 + B - 1) / B);
  const int gb  = (N + 63) / 64;
  const long long tot2 = (long long)N * 64;
  const int cb  = (int)((tot2 + B - 1) / B);
  const int gN  = (N + 2047) / 2048;

  ushort* Wp1l = Wp + 0 * 16384;
  ushort* Wp1r = Wp + 1 * 16384;
  ushort* Wp2l = Wp + 2 * 16384;
  ushort* Wp2r = Wp + 3 * 16384;
  ushort* Wp3l = Wp + 4 * 16384;
  ushort* Wp3r = Wp + 5 * 16384;
  ushort* Wpln = Wp + 6 * 16384;

  // ---- CSR build: sharded count + deterministic-position region scatter ----
  detect_kernel<<<1, 1024, 0, stream>>>(ei, E, flag);
  zero_i32_kernel<<<(M + B - 1) / B, B, 0, stream>>>(cnt8, (long long)M);
  extract_count_kernel<<<eb, B, 0, stream>>>(ei, E, flag, es, r8, cnt8, N);
  cumnode_kernel<<<nb, B, 0, stream>>>(cnt8, cum8, cnt_node, N);
  partial_kernel<<<gN, B, 0, stream>>>(cnt_node, bsum, N);
  scanb_kernel<<<1, 512, 0, stream>>>(bsum, gN);
  offsets_kernel<<<gN, B, 0, stream>>>(cnt_node, bsum, off_node, N, E);
  pos_kernel<<<eb, B, 0, stream>>>(ei, E, flag, r8, off_node, cum8, ppk, N);
  for (uint32 p = 0; p < 4; ++p)
    scatter_det_kernel<<<eb, B, 0, stream>>>(es, ppk, E, p, esrc);

  // ---- bf16 conversion + weight repack (B1 aliases cnt8/cum8/ppk: CSR done) ----
  convert_bf16_kernel<<<cb, B, 0, stream>>>(x, B1, tot2);
  repack_w_kernel<<<8, B, 0, stream>>>(W1l, Wp1l);
  repack_w_kernel<<<8, B, 0, stream>>>(W1r, Wp1r);
  repack_w_kernel<<<8, B, 0, stream>>>(W2l, Wp2l);
  repack_w_kernel<<<8, B, 0, stream>>>(W2r, Wp2r);
  repack_w_kernel<<<8, B, 0, stream>>>(W3l, Wp3l);
  repack_w_kernel<<<8, B, 0, stream>>>(W3r, Wp3r);
  repack_w_kernel<<<8, B, 0, stream>>>(Wlin, Wpln);

  // ---- layer 1: x1 = elu(bn(agg(x)@W1l + b1 + x@W1r)) -> B3
  aggregate_bf16_kernel<<<wb, B, 0, stream>>>(B1, off_node, esrc, B2, N);
  zero_f32_kernel<<<64, B, 0, stream>>>(bnsum, 64 * 256);
  gemm_mfma_kernel<<<gb, B, 0, stream>>>((const ushort*)B2, Wp1l, (const ushort*)B1, Wp1r,
                                         nullptr, b1, nullptr, Ybuf, nullptr, bnsum, N);
  bn_finalize_kernel<<<1, 128, 0, stream>>>(bnsum, bnp, N);
  bn_elu_kernel<<<cb, B, 0, stream>>>((const uint32*)Ybuf, bnp, g1, be1, nullptr, B3, tot2);

  // ---- layer 2: Y=agg(x1)@W2l + x1@W2r ; R=x1@Wlin+blin ; x2 = elu(bn(Y)) + R -> B2
  aggregate_bf16_kernel<<<wb, B, 0, stream>>>(B3, off_node, esrc, B2, N);
  zero_f32_kernel<<<64, B, 0, stream>>>(bnsum, 64 * 256);
  gemm_mfma_kernel<<<gb, B, 0, stream>>>((const ushort*)B2, Wp2l, (const ushort*)B3, Wp2r,
                                         Wpln, b2, blin, Ybuf, (ushort*)B1, bnsum, N);
  bn_finalize_kernel<<<1, 128, 0, stream>>>(bnsum, bnp, N);
  bn_elu_kernel<<<cb, B, 0, stream>>>((const uint32*)Ybuf, bnp, g2, be2, B1, B2, tot2);

  // ---- layer 3: same, x3 -> B3
  aggregate_bf16_kernel<<<wb, B, 0, stream>>>(B2, off_node, esrc, B3, N);
  zero_f32_kernel<<<64, B, 0, stream>>>(bnsum, 64 * 256);
  gemm_mfma_kernel<<<gb, B, 0, stream>>>((const ushort*)B3, Wp3l, (const ushort*)B2, Wp3r,
                                         Wpln, b3, blin, Ybuf, (ushort*)B1, bnsum, N);
  bn_finalize_kernel<<<1, 128, 0, stream>>>(bnsum, bnp, N);
  bn_elu_kernel<<<cb, B, 0, stream>>>((const uint32*)Ybuf, bnp, g3, be3, B1, B3, tot2);

  // ---- layer 4: out = mean_agg(x3@W4l) + b4 + x3@W4r (aggregate scalars)
  dot4_kernel<<<wb, B, 0, stream>>>(B3, W4l, W4r, z, rr, N);
  final_kernel<<<nb, B, 0, stream>>>(z, rr, off_node, esrc, b4, out, N);
}

// Round 10
// 992.519 us; speedup vs baseline: 1.1692x; 1.1692x over previous
//
#include <hip/hip_runtime.h>
#include <hip/hip_bf16.h>
#include <math.h>

#define BN_EPS 1e-5f

typedef __attribute__((ext_vector_type(8))) short bf16x8;
typedef __attribute__((ext_vector_type(4))) float f32x4;
typedef unsigned int uint32;

// ---------------- bf16 helpers ----------------
__device__ __forceinline__ unsigned bf16rne(float f) {
  unsigned u = __float_as_uint(f);
  unsigned r = u + 0x7fffu + ((u >> 16) & 1u);
  return r >> 16;
}
__device__ __forceinline__ float bf2f_lo(uint32 u) { return __uint_as_float(u << 16); }
__device__ __forceinline__ float bf2f_hi(uint32 u) { return __uint_as_float(u & 0xffff0000u); }
__device__ __forceinline__ uint32 packbf2(float a, float b) {
  return bf16rne(a) | (bf16rne(b) << 16);
}

// ---------------- edge index access (int32 vs int64 layout) ----------------
__device__ __forceinline__ int edge_at(const int* __restrict__ ei, long long idx, int is64) {
  return is64 ? ei[2 * idx] : ei[idx];
}

__global__ void detect_kernel(const int* __restrict__ ei, long long E, int* __restrict__ flag) {
  __shared__ int found;
  int t = threadIdx.x;
  if (t == 0) found = 0;
  __syncthreads();
  long long npairs = E < 1024 ? E : 1024;
  for (long long p = t; p < npairs; p += blockDim.x)
    if (ei[2 * p + 1] != 0) found = 1;
  __syncthreads();
  if (t == 0) *flag = found ? 0 : 1;  // all hi-words zero => int64
}

// ---------------- utility zero kernels ----------------
__global__ void zero_i32_kernel(int* __restrict__ p, long long n) {
  long long i = blockIdx.x * (long long)blockDim.x + threadIdx.x;
  if (i < n) p[i] = 0;
}
__global__ void zero_f32_kernel(float* __restrict__ p, long long n) {
  long long i = blockIdx.x * (long long)blockDim.x + threadIdx.x;
  if (i < n) p[i] = 0.f;
}

// ---------------- CSR build ----------------
// Pass 1: extract src, XCD-sharded count (shadow = blockIdx&7), record shadow-rank.
__global__ void extract_count_kernel(const int* __restrict__ ei, long long E,
                                     const int* __restrict__ flag,
                                     int* __restrict__ es, int* __restrict__ r8,
                                     int* __restrict__ cnt8, int N) {
  long long e = blockIdx.x * (long long)blockDim.x + threadIdx.x;
  if (e >= E) return;
  int is64 = *flag;
  es[e] = edge_at(ei, e, is64);
  int d = edge_at(ei, E + e, is64);
  int sh = blockIdx.x & 7;
  r8[e] = atomicAdd(&cnt8[(size_t)sh * N + d], 1);
}

// per-node exclusive prefix across shadows; total degree -> cnt_node
__global__ void cumnode_kernel(const int* __restrict__ cnt8, int* __restrict__ cum8,
                               int* __restrict__ cnt_node, int N) {
  int n = blockIdx.x * blockDim.x + threadIdx.x;
  if (n >= N) return;
  int run = 0;
#pragma unroll
  for (int sh = 0; sh < 8; ++sh) {
    int c = cnt8[(size_t)sh * N + n];
    cum8[(size_t)sh * N + n] = run;
    run += c;
  }
  cnt_node[n] = run;
}

// ---- two-level scan ----
__global__ void partial_kernel(const int* __restrict__ cnt, int* __restrict__ bsum, int M) {
  __shared__ int s[256];
  int b = blockIdx.x, t = threadIdx.x;
  int base = b * 2048 + t * 8;
  int sum = 0;
#pragma unroll
  for (int i = 0; i < 8; ++i) {
    int idx = base + i;
    if (idx < M) sum += cnt[idx];
  }
  s[t] = sum;
  __syncthreads();
  for (int d = 128; d > 0; d >>= 1) {
    if (t < d) s[t] += s[t + d];
    __syncthreads();
  }
  if (t == 0) bsum[b] = s[0];
}

__global__ void scanb_kernel(int* __restrict__ bsum, int nb) {
  __shared__ int s[512];
  int t = threadIdx.x;
  int v = (t < nb) ? bsum[t] : 0;
  s[t] = v;
  __syncthreads();
  for (int d = 1; d < 512; d <<= 1) {
    int u = (t >= d) ? s[t - d] : 0;
    __syncthreads();
    s[t] += u;
    __syncthreads();
  }
  if (t < nb) bsum[t] = s[t] - v;  // exclusive
}

__global__ void offsets_kernel(const int* __restrict__ cnt, const int* __restrict__ bsum,
                               int* __restrict__ off, int M, long long Etot) {
  __shared__ int s[256];
  int b = blockIdx.x, t = threadIdx.x;
  int base = b * 2048 + t * 8;
  int v[8];
  int sum = 0;
#pragma unroll
  for (int i = 0; i < 8; ++i) {
    int idx = base + i;
    v[i] = (idx < M) ? cnt[idx] : 0;
    sum += v[i];
  }
  s[t] = sum;
  __syncthreads();
  for (int d = 1; d < 256; d <<= 1) {
    int u = (t >= d) ? s[t - d] : 0;
    __syncthreads();
    s[t] += u;
    __syncthreads();
  }
  int run = bsum[b] + s[t] - sum;
#pragma unroll
  for (int i = 0; i < 8; ++i) {
    int idx = base + i;
    if (idx < M) {
      off[idx] = run;
      run += v[i];
    }
  }
  if (b == 0 && t == 0) off[M] = (int)Etot;
}

// pos[e] = off_node[d] + cum8[sh][d] + r8[e]; pack region (d>>15, N<=131072) in bits 28+.
__global__ void pos_kernel(const int* __restrict__ ei, long long E, const int* __restrict__ flag,
                           const int* __restrict__ r8, const int* __restrict__ off_node,
                           const int* __restrict__ cum8, uint32* __restrict__ ppk, int N) {
  long long e = blockIdx.x * (long long)blockDim.x + threadIdx.x;
  if (e >= E) return;
  int is64 = *flag;
  int d = edge_at(ei, E + e, is64);
  int sh = blockIdx.x & 7;  // must match extract_count grid mapping
  uint32 pos = (uint32)(off_node[d] + cum8[(size_t)sh * N + d] + r8[e]);
  uint32 region = (uint32)d >> 15;
  ppk[e] = pos | (region << 28);
}

// deterministic region-pass scatter: no atomics; writes land node-major in a
// ~3.2 MB L2-resident window per pass (full-degree buckets -> full lines)
__global__ void scatter_det_kernel(const int* __restrict__ es, const uint32* __restrict__ ppk,
                                   long long E, uint32 p, int* __restrict__ esrc) {
  long long e = blockIdx.x * (long long)blockDim.x + threadIdx.x;
  if (e >= E) return;
  uint32 v = ppk[e];
  if ((v >> 28) == p) esrc[v & 0x0FFFFFFFu] = es[e];
}

// ---------------- fp32 -> packed bf16 rows ----------------
__global__ void convert_bf16_kernel(const float* __restrict__ x, uint32* __restrict__ xb,
                                    long long total2) {
  long long i = blockIdx.x * (long long)blockDim.x + threadIdx.x;
  if (i >= total2) return;
  float2 f = ((const float2*)x)[i];
  xb[i] = packbf2(f.x, f.y);
}

// ---------------- merged weight repack: 7 x W[128][128] fp32 -> b-frag bf16 ----------------
// 8 blocks per weight; weight index = blockIdx>>3.
__global__ void repack_all_kernel(const float* __restrict__ Wa, const float* __restrict__ Wb,
                                  const float* __restrict__ Wc, const float* __restrict__ Wd,
                                  const float* __restrict__ We, const float* __restrict__ Wf,
                                  const float* __restrict__ Wg, ushort* __restrict__ Wp) {
  int wi = blockIdx.x >> 3;
  const float* W = wi == 0 ? Wa : wi == 1 ? Wb : wi == 2 ? Wc : wi == 3 ? Wd
                 : wi == 4 ? We : wi == 5 ? Wf : Wg;
  ushort* dst = Wp + (size_t)wi * 16384;
  int s = (blockIdx.x & 7) * 256 + threadIdx.x;
  int nt = s >> 8, rem = s & 255, ks = rem >> 6, lane = rem & 63;
  int q = lane >> 4, l16 = lane & 15;
  int kbase = ks * 32 + q * 8, c = nt * 16 + l16;
  uint32 out[4];
#pragma unroll
  for (int jp = 0; jp < 4; ++jp) {
    float a = W[(size_t)(kbase + 2 * jp) * 128 + c];
    float b = W[(size_t)(kbase + 2 * jp + 1) * 128 + c];
    out[jp] = packbf2(a, b);
  }
  ((uint4*)dst)[s] = make_uint4(out[0], out[1], out[2], out[3]);
}

// ---------------- mean aggregation v2: wave per node, 4 edges per load step ----------------
// lane = (grp:2 | sub:4): 16 lanes x uint4 cover one 256B row; grp selects edge.
// 2-deep unroll => 8 edges in flight per wave.
__global__ void aggregate_bf16_kernel(const uint32* __restrict__ X, const int* __restrict__ off,
                                      const int* __restrict__ esrc, uint32* __restrict__ out,
                                      int N) {
  int gw = (int)((blockIdx.x * (long long)blockDim.x + threadIdx.x) >> 6);
  int lane = threadIdx.x & 63;
  if (gw >= N) return;
  int b = off[gw], e = off[gw + 1];
  int sub = lane & 15, grp = lane >> 4;
  const uint4* X4 = (const uint4*)X;
  float acc[8];
#pragma unroll
  for (int j = 0; j < 8; ++j) acc[j] = 0.f;
  for (int i = b; i < e; i += 8) {
    int i0 = i + grp, i1 = i + 4 + grp;
    bool h0 = i0 < e, h1 = i1 < e;
    uint4 v0 = make_uint4(0, 0, 0, 0), v1 = make_uint4(0, 0, 0, 0);
    if (h0) { int s0 = esrc[i0]; v0 = X4[(size_t)s0 * 16 + sub]; }
    if (h1) { int s1 = esrc[i1]; v1 = X4[(size_t)s1 * 16 + sub]; }
    if (h0) {
      acc[0] += bf2f_lo(v0.x); acc[1] += bf2f_hi(v0.x);
      acc[2] += bf2f_lo(v0.y); acc[3] += bf2f_hi(v0.y);
      acc[4] += bf2f_lo(v0.z); acc[5] += bf2f_hi(v0.z);
      acc[6] += bf2f_lo(v0.w); acc[7] += bf2f_hi(v0.w);
    }
    if (h1) {
      acc[0] += bf2f_lo(v1.x); acc[1] += bf2f_hi(v1.x);
      acc[2] += bf2f_lo(v1.y); acc[3] += bf2f_hi(v1.y);
      acc[4] += bf2f_lo(v1.z); acc[5] += bf2f_hi(v1.z);
      acc[6] += bf2f_lo(v1.w); acc[7] += bf2f_hi(v1.w);
    }
  }
#pragma unroll
  for (int j = 0; j < 8; ++j) {
    acc[j] += __shfl_xor(acc[j], 16, 64);
    acc[j] += __shfl_xor(acc[j], 32, 64);
  }
  if (grp == 0) {
    float inv = 1.0f / fmaxf((float)(e - b), 1.0f);
    uint4 o;
    o.x = packbf2(acc[0] * inv, acc[1] * inv);
    o.y = packbf2(acc[2] * inv, acc[3] * inv);
    o.z = packbf2(acc[4] * inv, acc[5] * inv);
    o.w = packbf2(acc[6] * inv, acc[7] * inv);
    ((uint4*)out)[(size_t)gw * 16 + sub] = o;
  }
}

// ---------------- MFMA GEMM: Y = A1@W1 + A2@W2 + bias ; optional R = A2@W3 + rbias ----------------
__launch_bounds__(256)
__global__ void gemm_mfma_kernel(const ushort* __restrict__ A1, const ushort* __restrict__ W1p,
                                 const ushort* __restrict__ A2, const ushort* __restrict__ W2p,
                                 const ushort* __restrict__ W3p,
                                 const float* __restrict__ bias, const float* __restrict__ rbias,
                                 ushort* __restrict__ Y, ushort* __restrict__ R,
                                 float* __restrict__ bnsum, int N) {
  __shared__ float sred[16][128];
  int t = threadIdx.x;
  int w = t >> 6, lane = t & 63;
  int quad = lane >> 4, l16 = lane & 15;
  int row0 = blockIdx.x * 64 + w * 16;

  f32x4 accY[8], accR[8];
#pragma unroll
  for (int nt = 0; nt < 8; ++nt) {
    accY[nt][0] = accY[nt][1] = accY[nt][2] = accY[nt][3] = 0.f;
    accR[nt][0] = accR[nt][1] = accR[nt][2] = accR[nt][3] = 0.f;
  }

  int rowA = row0 + l16;
  if (rowA > N - 1) rowA = N - 1;
  const ushort* a1p = A1 + (size_t)rowA * 128 + quad * 8;
  const ushort* a2p = A2 + (size_t)rowA * 128 + quad * 8;
  const int haveR = (W3p != nullptr);

#pragma unroll
  for (int ks = 0; ks < 4; ++ks) {
    bf16x8 a = *(const bf16x8*)(a1p + ks * 32);
#pragma unroll
    for (int nt = 0; nt < 8; ++nt) {
      bf16x8 b = *(const bf16x8*)(W1p + ((size_t)(nt * 4 + ks) * 64 + lane) * 8);
      accY[nt] = __builtin_amdgcn_mfma_f32_16x16x32_bf16(a, b, accY[nt], 0, 0, 0);
    }
  }
#pragma unroll
  for (int ks = 0; ks < 4; ++ks) {
    bf16x8 a = *(const bf16x8*)(a2p + ks * 32);
#pragma unroll
    for (int nt = 0; nt < 8; ++nt) {
      bf16x8 b = *(const bf16x8*)(W2p + ((size_t)(nt * 4 + ks) * 64 + lane) * 8);
      accY[nt] = __builtin_amdgcn_mfma_f32_16x16x32_bf16(a, b, accY[nt], 0, 0, 0);
    }
    if (haveR) {
#pragma unroll
      for (int nt = 0; nt < 8; ++nt) {
        bf16x8 b = *(const bf16x8*)(W3p + ((size_t)(nt * 4 + ks) * 64 + lane) * 8);
        accR[nt] = __builtin_amdgcn_mfma_f32_16x16x32_bf16(a, b, accR[nt], 0, 0, 0);
      }
    }
  }

  float s1v[8], s2v[8];
#pragma unroll
  for (int nt = 0; nt < 8; ++nt) {
    int c = nt * 16 + l16;
    float bv = bias[c];
    s1v[nt] = 0.f; s2v[nt] = 0.f;
#pragma unroll
    for (int reg = 0; reg < 4; ++reg) {
      int grow = row0 + quad * 4 + reg;
      if (grow < N) {
        float v = accY[nt][reg] + bv;
        Y[(size_t)grow * 128 + c] = (ushort)bf16rne(v);
        s1v[nt] += v; s2v[nt] += v * v;
      }
    }
    if (haveR) {
      float rb = rbias[c];
#pragma unroll
      for (int reg = 0; reg < 4; ++reg) {
        int grow = row0 + quad * 4 + reg;
        if (grow < N) {
          float v = accR[nt][reg] + rb;
          R[(size_t)grow * 128 + c] = (ushort)bf16rne(v);
        }
      }
    }
  }

  int rrow = w * 4 + quad;
#pragma unroll
  for (int nt = 0; nt < 8; ++nt) sred[rrow][nt * 16 + l16] = s1v[nt];
  __syncthreads();
  if (t < 128) {
    float tot = 0.f;
#pragma unroll
    for (int r16 = 0; r16 < 16; ++r16) tot += sred[r16][t];
    atomicAdd(&bnsum[(size_t)(blockIdx.x & 63) * 256 + t], tot);
  }
  __syncthreads();
#pragma unroll
  for (int nt = 0; nt < 8; ++nt) sred[rrow][nt * 16 + l16] = s2v[nt];
  __syncthreads();
  if (t < 128) {
    float tot = 0.f;
#pragma unroll
    for (int r16 = 0; r16 < 16; ++r16) tot += sred[r16][t];
    atomicAdd(&bnsum[(size_t)(blockIdx.x & 63) * 256 + 128 + t], tot);
  }
}

// ---------------- BN finalize over 64 shadows ----------------
__global__ void bn_finalize_kernel(const float* __restrict__ bnsum, float* __restrict__ bnp, int N) {
  int t = threadIdx.x;
  if (t < 128) {
    float s = 0.f, s2 = 0.f;
    for (int sh = 0; sh < 64; ++sh) {
      s  += bnsum[(size_t)sh * 256 + t];
      s2 += bnsum[(size_t)sh * 256 + 128 + t];
    }
    float invN = 1.0f / (float)N;
    float mu = s * invN;
    float var = s2 * invN - mu * mu;
    bnp[t] = mu;
    bnp[128 + t] = rsqrtf(var + BN_EPS);
  }
}

// ---------------- BN apply + ELU (+ residual), bf16 in/out ----------------
__global__ void bn_elu_kernel(const uint32* __restrict__ Y, const float* __restrict__ bnp,
                              const float* __restrict__ g, const float* __restrict__ be,
                              const uint32* __restrict__ res, uint32* __restrict__ Xo,
                              long long total2) {
  long long i = blockIdx.x * (long long)blockDim.x + threadIdx.x;
  if (i >= total2) return;
  int c0 = (int)(i & 63) * 2;
  uint32 y = Y[i];
  float v0 = g[c0]     * (bf2f_lo(y) - bnp[c0])     * bnp[128 + c0]     + be[c0];
  float v1 = g[c0 + 1] * (bf2f_hi(y) - bnp[c0 + 1]) * bnp[128 + c0 + 1] + be[c0 + 1];
  v0 = v0 > 0.f ? v0 : expm1f(v0);
  v1 = v1 > 0.f ? v1 : expm1f(v1);
  if (res) {
    uint32 rv = res[i];
    v0 += bf2f_lo(rv); v1 += bf2f_hi(rv);
  }
  Xo[i] = packbf2(v0, v1);
}

// ---------------- layer 4: z = x3@W4l, rr = x3@W4r (one wave per node) ----------------
__global__ void dot4_kernel(const uint32* __restrict__ X, const float* __restrict__ W4l,
                            const float* __restrict__ W4r, float* __restrict__ z,
                            float* __restrict__ rr, int N) {
  int gw = (int)((blockIdx.x * (long long)blockDim.x + threadIdx.x) >> 6);
  int lane = threadIdx.x & 63;
  if (gw >= N) return;
  uint32 u = X[(size_t)gw * 64 + lane];
  float x0 = bf2f_lo(u), x1 = bf2f_hi(u);
  float wl0 = W4l[2 * lane], wl1 = W4l[2 * lane + 1];
  float wr0 = W4r[2 * lane], wr1 = W4r[2 * lane + 1];
  float a = x0 * wl0 + x1 * wl1;
  float b = x0 * wr0 + x1 * wr1;
  for (int d = 32; d > 0; d >>= 1) {
    a += __shfl_down(a, d, 64);
    b += __shfl_down(b, d, 64);
  }
  if (lane == 0) { z[gw] = a; rr[gw] = b; }
}

// ---------------- layer 4 final: out = mean_agg(z) + b4 + rr ----------------
__global__ void final_kernel(const float* __restrict__ z, const float* __restrict__ rr,
                             const int* __restrict__ off, const int* __restrict__ esrc,
                             const float* __restrict__ b4, float* __restrict__ out, int N) {
  int n = blockIdx.x * blockDim.x + threadIdx.x;
  if (n >= N) return;
  int b = off[n], e = off[n + 1];
  float s = 0.f;
  for (int i = b; i < e; ++i) s += z[esrc[i]];
  out[n] = s / fmaxf((float)(e - b), 1.0f) + b4[0] + rr[n];
}

// ---------------- launch ----------------
extern "C" void kernel_launch(void* const* d_in, const int* in_sizes, int n_in,
                              void* d_out, int out_size, void* d_ws, size_t ws_size,
                              hipStream_t stream) {
  const float* x   = (const float*)d_in[0];
  const int*   ei  = (const int*)d_in[1];
  const float* W1l = (const float*)d_in[2];
  const float* b1  = (const float*)d_in[3];
  const float* W1r = (const float*)d_in[4];
  const float* W2l = (const float*)d_in[5];
  const float* b2  = (const float*)d_in[6];
  const float* W2r = (const float*)d_in[7];
  const float* W3l = (const float*)d_in[8];
  const float* b3  = (const float*)d_in[9];
  const float* W3r = (const float*)d_in[10];
  const float* W4l = (const float*)d_in[11];
  const float* b4  = (const float*)d_in[12];
  const float* W4r = (const float*)d_in[13];
  const float* g1  = (const float*)d_in[14];
  const float* be1 = (const float*)d_in[15];
  const float* g2  = (const float*)d_in[16];
  const float* be2 = (const float*)d_in[17];
  const float* g3  = (const float*)d_in[18];
  const float* be3 = (const float*)d_in[19];
  const float* Wlin= (const float*)d_in[20];
  const float* blin= (const float*)d_in[21];

  const int N = in_sizes[0] / 128;
  const long long E = in_sizes[1] / 2;
  const int M = 8 * N;
  float* out = (float*)d_out;

  char* w = (char*)d_ws;
  size_t o = 0;
  auto alloc = [&](size_t bytes) -> char* {
    char* p = w + o;
    o = (o + bytes + 255) & ~(size_t)255;
    return p;
  };
  // ---- dedicated (persistent) ----
  int*    off_node = (int*)alloc((size_t)(N + 1) * 4);
  int*    cnt_node = (int*)alloc((size_t)N * 4);
  int*    bsum     = (int*)alloc(512 * 4);
  int*    flag     = (int*)alloc(4);
  float*  bnsum    = (float*)alloc((size_t)64 * 256 * 4);
  float*  bnp      = (float*)alloc(256 * 4);
  float*  z        = (float*)alloc((size_t)N * 4);
  float*  rr       = (float*)alloc((size_t)N * 4);
  ushort* Wp       = (ushort*)alloc((size_t)7 * 2048 * 16);
  int*    esrc     = (int*)alloc((size_t)E * 4);   // final node-major edge list
  // ---- arena slots (lifetime-aliased) ----
  size_t slotA = (size_t)2 * E * 4;                // es | r8 -> later Ybuf
  size_t ysz = (size_t)N * 256;
  if (ysz > slotA) slotA = ysz;
  char* poolA  = alloc(slotA);
  char* poolB1 = alloc((size_t)N * 256);           // cnt8|cum8|ppk -> later B1
  char* poolB3 = alloc((size_t)N * 256);           // -> B3
  uint32* B2   = (uint32*)alloc((size_t)N * 256);
  (void)ws_size; (void)n_in; (void)out_size;

  int*    es    = (int*)poolA;
  int*    r8    = (int*)(poolA + (size_t)E * 4);
  ushort* Ybuf  = (ushort*)poolA;
  int*    cnt8  = (int*)poolB1;                    // 8N ints
  int*    cum8  = cnt8 + M;                        // 8N ints
  uint32* ppk   = (uint32*)(cum8 + M);             // E uints
  uint32* B1    = (uint32*)poolB1;
  uint32* B3    = (uint32*)poolB3;

  const int B = 256;
  const int eb  = (int)((E + B - 1) / B);
  const int nb  = (N + B - 1) / B;
  const int wb  = (int)(((long long)N * 64 + B - 1) / B);
  const int gb  = (N + 63) / 64;
  const long long tot2 = (long long)N * 64;
  const int cb  = (int)((tot2 + B - 1) / B);
  const int gN  = (N + 2047) / 2048;

  ushort* Wp1l = Wp + 0 * 16384;
  ushort* Wp1r = Wp + 1 * 16384;
  ushort* Wp2l = Wp + 2 * 16384;
  ushort* Wp2r = Wp + 3 * 16384;
  ushort* Wp3l = Wp + 4 * 16384;
  ushort* Wp3r = Wp + 5 * 16384;
  ushort* Wpln = Wp + 6 * 16384;

  // ---- CSR build: sharded count + deterministic-position region scatter ----
  detect_kernel<<<1, 1024, 0, stream>>>(ei, E, flag);
  zero_i32_kernel<<<(M + B - 1) / B, B, 0, stream>>>(cnt8, (long long)M);
  extract_count_kernel<<<eb, B, 0, stream>>>(ei, E, flag, es, r8, cnt8, N);
  cumnode_kernel<<<nb, B, 0, stream>>>(cnt8, cum8, cnt_node, N);
  partial_kernel<<<gN, B, 0, stream>>>(cnt_node, bsum, N);
  scanb_kernel<<<1, 512, 0, stream>>>(bsum, gN);
  offsets_kernel<<<gN, B, 0, stream>>>(cnt_node, bsum, off_node, N, E);
  pos_kernel<<<eb, B, 0, stream>>>(ei, E, flag, r8, off_node, cum8, ppk, N);
  for (uint32 p = 0; p < 4; ++p)
    scatter_det_kernel<<<eb, B, 0, stream>>>(es, ppk, E, p, esrc);

  // ---- bf16 conversion + merged weight repack (B1 aliases cnt8/cum8/ppk: CSR done) ----
  convert_bf16_kernel<<<cb, B, 0, stream>>>(x, B1, tot2);
  repack_all_kernel<<<56, B, 0, stream>>>(W1l, W1r, W2l, W2r, W3l, W3r, Wlin, Wp);

  // ---- layer 1: x1 = elu(bn(agg(x)@W1l + b1 + x@W1r)) -> B3
  aggregate_bf16_kernel<<<wb, B, 0, stream>>>(B1, off_node, esrc, B2, N);
  zero_f32_kernel<<<64, B, 0, stream>>>(bnsum, 64 * 256);
  gemm_mfma_kernel<<<gb, B, 0, stream>>>((const ushort*)B2, Wp1l, (const ushort*)B1, Wp1r,
                                         nullptr, b1, nullptr, Ybuf, nullptr, bnsum, N);
  bn_finalize_kernel<<<1, 128, 0, stream>>>(bnsum, bnp, N);
  bn_elu_kernel<<<cb, B, 0, stream>>>((const uint32*)Ybuf, bnp, g1, be1, nullptr, B3, tot2);

  // ---- layer 2: Y=agg(x1)@W2l + x1@W2r ; R=x1@Wlin+blin ; x2 = elu(bn(Y)) + R -> B2
  aggregate_bf16_kernel<<<wb, B, 0, stream>>>(B3, off_node, esrc, B2, N);
  zero_f32_kernel<<<64, B, 0, stream>>>(bnsum, 64 * 256);
  gemm_mfma_kernel<<<gb, B, 0, stream>>>((const ushort*)B2, Wp2l, (const ushort*)B3, Wp2r,
                                         Wpln, b2, blin, Ybuf, (ushort*)B1, bnsum, N);
  bn_finalize_kernel<<<1, 128, 0, stream>>>(bnsum, bnp, N);
  bn_elu_kernel<<<cb, B, 0, stream>>>((const uint32*)Ybuf, bnp, g2, be2, B1, B2, tot2);

  // ---- layer 3: same, x3 -> B3
  aggregate_bf16_kernel<<<wb, B, 0, stream>>>(B2, off_node, esrc, B3, N);
  zero_f32_kernel<<<64, B, 0, stream>>>(bnsum, 64 * 256);
  gemm_mfma_kernel<<<gb, B, 0, stream>>>((const ushort*)B3, Wp3l, (const ushort*)B2, Wp3r,
                                         Wpln, b3, blin, Ybuf, (ushort*)B1, bnsum, N);
  bn_finalize_kernel<<<1, 128, 0, stream>>>(bnsum, bnp, N);
  bn_elu_kernel<<<cb, B, 0, stream>>>((const uint32*)Ybuf, bnp, g3, be3, B1, B3, tot2);

  // ---- layer 4: out = mean_agg(x3@W4l) + b4 + x3@W4r (aggregate scalars)
  dot4_kernel<<<wb, B, 0, stream>>>(B3, W4l, W4r, z, rr, N);
  final_kernel<<<nb, B, 0, stream>>>(z, rr, off_node, esrc, b4, out, N);
}